// Round 12
// baseline (168.723 us; speedup 1.0000x reference)
//
#include <hip/hip_runtime.h>
#include <math.h>

#define B_   32
#define C_   32
#define T_   1024
#define NF_  33
#define F2_  66      // NF*2
#define FD_  2112    // C_*F2_
#define NW_  961
#define MLP_ 256
#define HID_ 256
#define HH_  128
#define TN_  32
#define NT_  31      // ceil(961/32)

#define PI_F     3.14159265358979323846f
#define LN2_F    0.69314718055994530942f
#define L2E2_F   2.88539008177792681472f   // 2*log2(e)

typedef unsigned short u16;
typedef unsigned int   u32;
typedef __attribute__((ext_vector_type(8))) short bf16x8;
typedef __attribute__((ext_vector_type(4))) float f32x4;

__device__ __forceinline__ u16 f2bf(float f) {
    u32 u = __float_as_uint(f);
    u = u + 0x7FFFu + ((u >> 16) & 1u);   // RNE
    return (u16)(u >> 16);
}
__device__ __forceinline__ float bf2f(u16 h) {
    return __uint_as_float((u32)h << 16);
}
__device__ __forceinline__ void gload16(const void* g, void* l) {
    __builtin_amdgcn_global_load_lds(
        (const __attribute__((address_space(1))) void*)g,
        (__attribute__((address_space(3))) void*)l, 16, 0, 0);
}
__device__ __forceinline__ float ftanh(float x) {
    float z = __builtin_amdgcn_exp2f(x * L2E2_F);
    return 1.f - 2.f * __builtin_amdgcn_rcpf(z + 1.f);
}
__device__ __forceinline__ float flog1p(float x) {
    return __builtin_amdgcn_logf(1.f + x) * LN2_F;   // v_log_f32 is log2
}
// atan2(y,x)/pi, poly max err ~2e-6 (in pi units)
__device__ __forceinline__ float fatan2pi(float y, float x) {
    const float ay = fabsf(y), ax = fabsf(x);
    const float mn = fminf(ay, ax), mx = fmaxf(ay, ax);
    float t = mn * __builtin_amdgcn_rcpf(mx);
    t = (mx == 0.f) ? 0.f : t;
    const float s = t * t;
    float p = -0.00373098f;
    p = fmaf(p, s,  0.01676008f);
    p = fmaf(p, s, -0.03706162f);
    p = fmaf(p, s,  0.06160679f);
    p = fmaf(p, s, -0.10587735f);
    p = fmaf(p, s,  0.31830265f);
    p *= t;
    p = (ay > ax) ? 0.5f - p : p;
    p = (x < 0.f) ? 1.0f - p : p;
    return copysignf(p, y);
}

// ---------------------------------------------------------------------------
// prepfeat: merged weight-conversion + softmax + sliding-DFT feature kernel.
// blocks [0,128): Wp hi/lo. [128,160): W1. [160,176): W2. 176: softmax +
// counter zero. [177, 177+124*nb): feat (tile, cg, bb decomposed).
// ---------------------------------------------------------------------------
__global__ __launch_bounds__(256, 4) void prepfeat_kernel(
        const float* __restrict__ x,
        const float* __restrict__ Wp, const float* __restrict__ W1,
        const float* __restrict__ W2, const float* __restrict__ agg,
        u16* __restrict__ WpH, u16* __restrict__ WpL,
        u16* __restrict__ W1H, u16* __restrict__ W1L,
        u16* __restrict__ W2H, u16* __restrict__ W2L,
        float* __restrict__ wts, int* __restrict__ cnt,
        u32* __restrict__ featP) {
    const int blk = blockIdx.x;
    const int tid = threadIdx.x;

    if (blk < 177) {
        if (blk < 128) {
            const int total = MLP_ * FD_;
            for (int i = blk * 256 + tid; i < total; i += 128 * 256) {
                const float v = Wp[i];
                const u16 h = f2bf(v);
                WpH[i] = h; WpL[i] = f2bf(v - bf2f(h));
            }
        } else if (blk < 160) {
            const int total = HID_ * MLP_;
            for (int i = (blk - 128) * 256 + tid; i < total; i += 32 * 256) {
                const float v = W1[i];
                const u16 h = f2bf(v);
                W1H[i] = h; W1L[i] = f2bf(v - bf2f(h));
            }
        } else if (blk < 176) {
            const int total = HH_ * HID_;
            for (int i = (blk - 160) * 256 + tid; i < total; i += 16 * 256) {
                const float v = W2[i];
                const u16 h = f2bf(v);
                W2H[i] = h; W2L[i] = f2bf(v - bf2f(h));
            }
        } else {
            __shared__ float red[256];
            if (tid == 0) *cnt = 0;
            float mx = -INFINITY;
            for (int i = tid; i < NW_; i += 256) mx = fmaxf(mx, agg[i]);
            red[tid] = mx; __syncthreads();
            for (int s = 128; s > 0; s >>= 1) {
                if (tid < s) red[tid] = fmaxf(red[tid], red[tid + s]);
                __syncthreads();
            }
            mx = red[0]; __syncthreads();
            float sm = 0.f;
            for (int i = tid; i < NW_; i += 256) sm += expf(agg[i] - mx);
            red[tid] = sm; __syncthreads();
            for (int s = 128; s > 0; s >>= 1) {
                if (tid < s) red[tid] += red[tid + s];
                __syncthreads();
            }
            const float inv = 1.f / red[0];
            for (int i = tid; i < NW_; i += 256) wts[i] = expf(agg[i] - mx) * inv;
        }
        return;
    }

    // ---- feat part ----
    const int fb = blk - 177;
    const int bb = fb / 124;
    const int r2 = fb - bb * 124;
    const int cg = r2 / 31;
    const int n0 = (r2 - cg * 31) * TN_;
    const int tf = tid & 31;     // bin 0..31
    const int c8 = tid >> 5;     // channel-in-group 0..7
    const int c  = cg * 8 + c8;

    __shared__ float2 stab[64];
    __shared__ float xs[8][96];
    __shared__ float basisT[64][68];

    if (tid < 64) {
        float s, cc;
        sincosf(-PI_F * (float)tid / 32.0f, &s, &cc);
        stab[tid] = make_float2(cc, s);
    }
    __syncthreads();
    for (int e = tid; e < 2048; e += 256) {
        const int f = e >> 6, k = e & 63;
        const float2 w = stab[(f * k) & 63];
        basisT[k][2 * f]     = w.x;
        basisT[k][2 * f + 1] = w.y;
    }
    if (tid < 192) {
        const int cs = tid / 24, q = tid % 24;
        const int t0 = n0 + q * 4;
        const float* xb = x + ((size_t)bb * C_ + cg * 8 + cs) * T_;
        float4 v;
        if (t0 + 3 < T_) {
            v = *(const float4*)(xb + t0);
        } else {
            v.x = (t0 + 0 < T_) ? xb[t0 + 0] : 0.f;
            v.y = (t0 + 1 < T_) ? xb[t0 + 1] : 0.f;
            v.z = (t0 + 2 < T_) ? xb[t0 + 2] : 0.f;
            v.w = 0.f;
        }
        *(float4*)&xs[cs][q * 4] = v;
    }
    __syncthreads();

    const size_t rowb = (size_t)bb * NW_;

    // phase 1: bins 0..31, sliding across 32 windows
    {
        float re = 0.f, im = 0.f;
#pragma unroll
        for (int k = 0; k < 64; ++k) {
            const float xv = xs[c8][k];
            const float2 w = *(const float2*)&basisT[k][2 * tf];
            re = fmaf(xv, w.x, re);
            im = fmaf(xv, w.y, im);
        }
        const float2 st = stab[tf];
        const float cx = st.x, sx = -st.y;

        for (int j = 0; j < TN_; ++j) {
            const int gn = n0 + j;
            if (gn >= NW_) break;
            const float r   = __builtin_amdgcn_sqrtf(re * re + im * im);
            const float mag = flog1p(r);
            const float ph  = fatan2pi(im, re);
            featP[(rowb + gn) * (FD_ / 2) + 33 * c + tf] =
                (u32)f2bf(mag) | ((u32)f2bf(ph) << 16);
            const float tre = re - xs[c8][j] + xs[c8][j + 64];
            re = tre * cx - im * sx;
            im = tre * sx + im * cx;
        }
    }

    // phase 2: Nyquist bin
    {
        const int j   = tid & 31;
        const int c8n = tid >> 5;
        const int gn  = n0 + j;
        if (gn < NW_) {
            float s = 0.f;
#pragma unroll
            for (int k = 0; k < 32; ++k)
                s += xs[c8n][j + 2 * k] - xs[c8n][j + 2 * k + 1];
            const float a = flog1p(fabsf(s));
            const float p = (__float_as_uint(s) >> 31) ? 1.0f : 0.0f;
            featP[(rowb + gn) * (FD_ / 2) + 33 * (cg * 8 + c8n) + 32] =
                (u32)f2bf(a) | ((u32)f2bf(p) << 16);
        }
    }
}

// ---------------------------------------------------------------------------
// gemm3p: 4-buffer DEPTH-3 counted-vmcnt MFMA pipeline. BM=128 x BN=256,
// BK=32, 512 thr / 8 waves (2x4 of 64x64), 2-term. LDS = 160KB (HW max;
// AITER precedent). Per K-step: {vmcnt(10|5|0); s_barrier; stage(t+3);
// MFMA}. Barrier-before-stage still protects buf (t+3)%4 == (t-1)%4.
// ---------------------------------------------------------------------------
__global__ __launch_bounds__(512, 2) void gemm3p_kernel(
        const u16* __restrict__ A,
        const u16* __restrict__ BH, const u16* __restrict__ BL,
        const float* __restrict__ bias, float scale,
        u16* __restrict__ outH, int Mvalid, int Kd) {
    constexpr int BNB   = 16384;
    constexpr int STEPB = 8192 + 2 * BNB;   // 40960
    __shared__ char lds[4 * STEPB];         // 163840 = 160 KB

    const int bm = blockIdx.x;
    const int tid = threadIdx.x;
    const int lane = tid & 63, w = tid >> 6;
    const int wr = w >> 2, wc = w & 3;
    const int m0 = bm * 128;

    f32x4 acc[4][4];
#pragma unroll
    for (int i = 0; i < 4; ++i)
#pragma unroll
        for (int j = 0; j < 4; ++j) acc[i][j] = (f32x4){0.f, 0.f, 0.f, 0.f};

    const size_t rs = (size_t)Kd * 2;
    const char* gA  = (const char*)A + (size_t)m0 * rs;
    const char* gBH = (const char*)BH;
    const char* gBL = (const char*)BL;

    auto st1 = [&](const char* g, char* l, int idx) {
        const int row = idx >> 2;
        const int kc  = (idx & 3) ^ ((row >> 1) & 3);
        gload16(g + (size_t)row * rs + (size_t)(kc << 4), l + idx * 16);
    };
    auto stage = [&](int buf, int t) {
        const size_t k0b = (size_t)t << 6;
        char* lb = lds + buf * STEPB;
        st1(gA + k0b, lb, tid);
        st1(gBH + k0b, lb + 8192, tid);
        st1(gBH + k0b, lb + 8192, tid + 512);
        st1(gBL + k0b, lb + 8192 + BNB, tid);
        st1(gBL + k0b, lb + 8192 + BNB, tid + 512);
    };

    const int ra_ = wr * 64 + (lane & 15);
    const int rb_ = wc * 64 + (lane & 15);
    const int q   = lane >> 4;
    const int abase = ra_ * 64 + ((q ^ ((ra_ >> 1) & 3)) << 4);
    const int bbase = rb_ * 64 + ((q ^ ((rb_ >> 1) & 3)) << 4);

    const int nt = Kd >> 5;   // >= 8 for all our layers

    stage(0, 0);
    stage(1, 1);
    stage(2, 2);

    int cur = 0;
    for (int t = 0; t < nt; ++t) {
        if (t + 2 < nt)
            asm volatile("s_waitcnt vmcnt(10)" ::: "memory");
        else if (t + 1 < nt)
            asm volatile("s_waitcnt vmcnt(5)" ::: "memory");
        else
            asm volatile("s_waitcnt vmcnt(0)" ::: "memory");
        __builtin_amdgcn_sched_barrier(0);
        __builtin_amdgcn_s_barrier();
        asm volatile("" ::: "memory");

        int pf = cur + 3; if (pf >= 4) pf -= 4;
        if (t + 3 < nt) stage(pf, t + 3);

        const char* lb = lds + cur * STEPB;
        bf16x8 a4[4], bh4[4], bl4[4];
#pragma unroll
        for (int f = 0; f < 4; ++f) {
            a4[f]  = *(const bf16x8*)(lb + abase + f * 1024);
            bh4[f] = *(const bf16x8*)(lb + 8192 + bbase + f * 1024);
            bl4[f] = *(const bf16x8*)(lb + 8192 + BNB + bbase + f * 1024);
        }
        __builtin_amdgcn_s_setprio(1);
#pragma unroll
        for (int fm = 0; fm < 4; ++fm)
#pragma unroll
            for (int fn = 0; fn < 4; ++fn) {
                acc[fm][fn] = __builtin_amdgcn_mfma_f32_16x16x32_bf16(a4[fm], bh4[fn], acc[fm][fn], 0, 0, 0);
                acc[fm][fn] = __builtin_amdgcn_mfma_f32_16x16x32_bf16(a4[fm], bl4[fn], acc[fm][fn], 0, 0, 0);
            }
        __builtin_amdgcn_s_setprio(0);
        ++cur; if (cur >= 4) cur -= 4;
    }

    float bv[4];
#pragma unroll
    for (int fn = 0; fn < 4; ++fn) bv[fn] = bias[wc * 64 + fn * 16 + (lane & 15)];
#pragma unroll
    for (int fm = 0; fm < 4; ++fm) {
        const int rbase = m0 + wr * 64 + fm * 16 + (lane >> 4) * 4;
#pragma unroll
        for (int fn = 0; fn < 4; ++fn) {
            const int col = wc * 64 + fn * 16 + (lane & 15);
#pragma unroll
            for (int r = 0; r < 4; ++r) {
                const int row = rbase + r;
                if (row < Mvalid) {
                    const float v = ftanh(acc[fm][fn][r] + bv[fn]) * scale;
                    outH[(size_t)row * 256 + col] = f2bf(v);
                }
            }
        }
    }
}

// ---------------------------------------------------------------------------
// gemm3f: fused final layer + weighted reduction + LAST-BLOCK final sum.
// 3-buffer depth-2 main loop at BM=128 x BN=128 (2x2 waves, 256 thr).
// Epilogue: h2 = tanh(acc+b2), rowdot via shfl_xor + LDS combine,
// val = (rowdot+bout)*wts[n], deterministic per-b tree -> partial slots.
// Then device-scope atomic counter; last block sums partials in fixed
// order -> out[b]. Counter zeroed by prepfeat each call.
// ---------------------------------------------------------------------------
__global__ __launch_bounds__(256, 2) void gemm3f_kernel(
        const u16* __restrict__ A,
        const u16* __restrict__ BH, const u16* __restrict__ BL,
        const float* __restrict__ b2, const float* __restrict__ Wout,
        const float* __restrict__ bout, const float* __restrict__ wts,
        float* __restrict__ partial, int* __restrict__ cnt,
        float* __restrict__ outp, int nbat, int Mvalid, int Kd) {
    constexpr int BNB   = 8192;
    constexpr int STEPB = 8192 + 2 * BNB;   // 24576
    __shared__ char lds[3 * STEPB];         // 73728
    __shared__ int lastf;

    const int bm = blockIdx.x;
    const int tid = threadIdx.x;
    const int lane = tid & 63, w = tid >> 6;
    const int wr = w >> 1, wc = w & 1;
    const int m0 = bm * 128;

    f32x4 acc[4][4];
#pragma unroll
    for (int i = 0; i < 4; ++i)
#pragma unroll
        for (int j = 0; j < 4; ++j) acc[i][j] = (f32x4){0.f, 0.f, 0.f, 0.f};

    const size_t rs = (size_t)Kd * 2;
    const char* gA  = (const char*)A + (size_t)m0 * rs;
    const char* gBH = (const char*)BH;
    const char* gBL = (const char*)BL;

    auto st1 = [&](const char* g, char* l, int idx) {
        const int row = idx >> 2;
        const int kc  = (idx & 3) ^ ((row >> 1) & 3);
        gload16(g + (size_t)row * rs + (size_t)(kc << 4), l + idx * 16);
    };
    auto stage = [&](int buf, int t) {
        const size_t k0b = (size_t)t << 6;
        char* lb = lds + buf * STEPB;
        st1(gA + k0b, lb, tid);
        st1(gA + k0b, lb, tid + 256);
        st1(gBH + k0b, lb + 8192, tid);
        st1(gBH + k0b, lb + 8192, tid + 256);
        st1(gBL + k0b, lb + 8192 + BNB, tid);
        st1(gBL + k0b, lb + 8192 + BNB, tid + 256);
    };

    const int ra_ = wr * 64 + (lane & 15);
    const int rb_ = wc * 64 + (lane & 15);
    const int q   = lane >> 4;
    const int abase = ra_ * 64 + ((q ^ ((ra_ >> 1) & 3)) << 4);
    const int bbase = rb_ * 64 + ((q ^ ((rb_ >> 1) & 3)) << 4);

    const int nt = Kd >> 5;

    stage(0, 0);
    stage(1, 1);

    int cur = 0;
    for (int t = 0; t < nt; ++t) {
        if (t + 1 < nt)
            asm volatile("s_waitcnt vmcnt(6)" ::: "memory");
        else
            asm volatile("s_waitcnt vmcnt(0)" ::: "memory");
        __builtin_amdgcn_sched_barrier(0);
        __builtin_amdgcn_s_barrier();
        asm volatile("" ::: "memory");

        int pf = cur + 2; if (pf >= 3) pf -= 3;
        if (t + 2 < nt) stage(pf, t + 2);

        const char* lb = lds + cur * STEPB;
        bf16x8 a4[4], bh4[4], bl4[4];
#pragma unroll
        for (int f = 0; f < 4; ++f) {
            a4[f]  = *(const bf16x8*)(lb + abase + f * 1024);
            bh4[f] = *(const bf16x8*)(lb + 8192 + bbase + f * 1024);
            bl4[f] = *(const bf16x8*)(lb + 8192 + BNB + bbase + f * 1024);
        }
        __builtin_amdgcn_s_setprio(1);
#pragma unroll
        for (int fm = 0; fm < 4; ++fm)
#pragma unroll
            for (int fn = 0; fn < 4; ++fn) {
                acc[fm][fn] = __builtin_amdgcn_mfma_f32_16x16x32_bf16(a4[fm], bh4[fn], acc[fm][fn], 0, 0, 0);
                acc[fm][fn] = __builtin_amdgcn_mfma_f32_16x16x32_bf16(a4[fm], bl4[fn], acc[fm][fn], 0, 0, 0);
            }
        __builtin_amdgcn_s_setprio(0);
        ++cur; if (cur >= 3) cur -= 3;
    }

    // ---- fused epilogue ----
    __syncthreads();
    float* rsum = (float*)lds;               // [128][2]
    float* red  = (float*)(lds + 1024);      // [256]

    float bv[4], wv[4];
#pragma unroll
    for (int fn = 0; fn < 4; ++fn) {
        const int col = wc * 64 + fn * 16 + (lane & 15);
        bv[fn] = b2[col];
        wv[fn] = Wout[col];
    }
#pragma unroll
    for (int fm = 0; fm < 4; ++fm) {
#pragma unroll
        for (int r = 0; r < 4; ++r) {
            float c = 0.f;
#pragma unroll
            for (int fn = 0; fn < 4; ++fn)
                c += ftanh(acc[fm][fn][r] + bv[fn]) * wv[fn];
            c += __shfl_xor(c, 1);
            c += __shfl_xor(c, 2);
            c += __shfl_xor(c, 4);
            c += __shfl_xor(c, 8);
            if ((lane & 15) == 0)
                rsum[(wr * 64 + fm * 16 + (lane >> 4) * 4 + r) * 2 + wc] = c;
        }
    }
    __syncthreads();

    const float bO = bout[0];
    float val = 0.f;
    int rowb = -1;
    if (tid < 128) {
        const int gr = m0 + tid;
        if (gr < Mvalid) {
            const float dot = rsum[tid * 2] + rsum[tid * 2 + 1] + bO;
            rowb = gr / NW_;
            val = dot * wts[gr - rowb * NW_];
        }
    }
    __syncthreads();

    const int bFirst = m0 / NW_;
    red[tid] = (tid < 128 && rowb == bFirst) ? val : 0.f;
    __syncthreads();
    for (int s = 128; s > 0; s >>= 1) {
        if (tid < s) red[tid] += red[tid + s];
        __syncthreads();
    }
    if (tid == 0) partial[bm * 2] = red[0];
    __syncthreads();
    red[tid] = (tid < 128 && rowb == bFirst + 1) ? val : 0.f;
    __syncthreads();
    for (int s = 128; s > 0; s >>= 1) {
        if (tid < s) red[tid] += red[tid + s];
        __syncthreads();
    }
    if (tid == 0) partial[bm * 2 + 1] = red[0];

    // ---- last-block final reduction (deterministic fixed order) ----
    if (tid == 0) {
        __threadfence();                          // publish partials
        const int prev = atomicAdd(cnt, 1);
        lastf = (prev == (int)gridDim.x - 1) ? 1 : 0;
    }
    __syncthreads();
    if (lastf) {
        __threadfence();                          // acquire
        if (tid < nbat) {
            const int b = tid;
            const int nblocks = (int)gridDim.x;
            int lo = (b * NW_) / 128;
            int hi = ((b + 1) * NW_ - 1) / 128;
            if (hi > nblocks - 1) hi = nblocks - 1;
            float s = 0.f;
            for (int bm2 = lo; bm2 <= hi; ++bm2) {
                const int slot = ((bm2 * 128) / NW_ == b) ? 0 : 1;
                s += partial[bm2 * 2 + slot];
            }
            outp[b] = s;
        }
    }
}

// ---------------------------------------------------------------------------
extern "C" void kernel_launch(void* const* d_in, const int* in_sizes, int n_in,
                              void* d_out, int out_size, void* d_ws, size_t ws_size,
                              hipStream_t stream) {
    const float* x    = (const float*)d_in[0];
    const float* Wp   = (const float*)d_in[1];
    const float* bp   = (const float*)d_in[2];
    const float* W1   = (const float*)d_in[3];
    const float* b1   = (const float*)d_in[4];
    const float* W2   = (const float*)d_in[5];
    const float* b2   = (const float*)d_in[6];
    const float* Wout = (const float*)d_in[7];
    const float* bout = (const float*)d_in[8];
    const float* agg  = (const float*)d_in[9];
    float* out = (float*)d_out;

    char* wsb = (char*)d_ws;
    size_t off = 0;
    auto ra = [](size_t b) { return (b + 255) & ~(size_t)255; };
    auto alloc = [&](size_t bytes) -> char* {
        char* p = wsb + off;
        off += ra(bytes);
        return p;
    };

    u16* WpH = (u16*)alloc((size_t)MLP_ * FD_ * 2);
    u16* WpL = (u16*)alloc((size_t)MLP_ * FD_ * 2);
    u16* W1H = (u16*)alloc((size_t)HID_ * MLP_ * 2);
    u16* W1L = (u16*)alloc((size_t)HID_ * MLP_ * 2);
    u16* W2H = (u16*)alloc((size_t)HH_ * HID_ * 2);
    u16* W2L = (u16*)alloc((size_t)HH_ * HID_ * 2);
    float* wts = (float*)alloc((size_t)NW_ * 4);
    int* cnt   = (int*)alloc(256);

    const size_t fixed = off;
    int NB = 32;
    for (;;) {
        const size_t M = (size_t)NB * NW_;
        const size_t Mp = ((M + 127) / 128) * 128;
        const size_t need = ra(Mp * FD_ * 2) +        // featH
                            ra(Mp * 256 * 2) +        // projH
                            ra(Mp * 256 * 2) +        // h1H
                            ra((Mp / 128) * 2 * 4);   // partial
        if (fixed + need <= ws_size || NB == 1) break;
        NB >>= 1;
    }
    const size_t Mmax  = (size_t)NB * NW_;
    const size_t MpMax = ((Mmax + 127) / 128) * 128;
    u16* featH = (u16*)alloc(MpMax * FD_ * 2);
    u16* projH = (u16*)alloc(MpMax * 256 * 2);
    u16* h1H   = (u16*)alloc(MpMax * 256 * 2);
    float* partial = (float*)alloc((MpMax / 128) * 2 * 4);

    for (int b0 = 0; b0 < B_; b0 += NB) {
        const int nb = (B_ - b0 < NB) ? (B_ - b0) : NB;
        const int M = nb * NW_;
        const int Mp = ((M + 127) / 128) * 128;

        // prep (weights, softmax, counter) + feat, one launch
        prepfeat_kernel<<<dim3(177 + 124 * nb), dim3(256), 0, stream>>>(
            x + (size_t)b0 * C_ * T_, Wp, W1, W2, agg,
            WpH, WpL, W1H, W1L, W2H, W2L, wts, cnt, (u32*)featH);

        // proj = tanh(feat @ Wp^T + bp) * pi   (K=2112, depth-3)
        gemm3p_kernel<<<dim3(Mp / 128), dim3(512), 0, stream>>>(
            featH, WpH, WpL, bp, PI_F, projH, M, FD_);

        // h1 = tanh(proj @ W1^T + b1)          (K=256, depth-3)
        gemm3p_kernel<<<dim3(Mp / 128), dim3(512), 0, stream>>>(
            projH, W1H, W1L, b1, 1.0f, h1H, M, MLP_);

        // fused: h2 GEMM + weighted reduce + last-block final sum
        gemm3f_kernel<<<dim3(Mp / 128), dim3(256), 0, stream>>>(
            h1H, W2H, W2L, b2, Wout, bout, wts, partial, cnt,
            out + b0, nb, M, HID_);
    }
}

// Round 13
// 155.174 us; speedup vs baseline: 1.0873x; 1.0873x over previous
//
#include <hip/hip_runtime.h>
#include <math.h>

#define B_   32
#define C_   32
#define T_   1024
#define NF_  33
#define F2_  66      // NF*2
#define FD_  2112    // C_*F2_
#define NW_  961
#define MLP_ 256
#define HID_ 256
#define HH_  128
#define TN_  32
#define NT_  31      // ceil(961/32)

#define PI_F     3.14159265358979323846f
#define LN2_F    0.69314718055994530942f
#define L2E2_F   2.88539008177792681472f   // 2*log2(e)

typedef unsigned short u16;
typedef unsigned int   u32;
typedef __attribute__((ext_vector_type(8))) short bf16x8;
typedef __attribute__((ext_vector_type(4))) float f32x4;

__device__ __forceinline__ u16 f2bf(float f) {
    u32 u = __float_as_uint(f);
    u = u + 0x7FFFu + ((u >> 16) & 1u);   // RNE
    return (u16)(u >> 16);
}
__device__ __forceinline__ float bf2f(u16 h) {
    return __uint_as_float((u32)h << 16);
}
__device__ __forceinline__ void gload16(const void* g, void* l) {
    __builtin_amdgcn_global_load_lds(
        (const __attribute__((address_space(1))) void*)g,
        (__attribute__((address_space(3))) void*)l, 16, 0, 0);
}
__device__ __forceinline__ float ftanh(float x) {
    float z = __builtin_amdgcn_exp2f(x * L2E2_F);
    return 1.f - 2.f * __builtin_amdgcn_rcpf(z + 1.f);
}
__device__ __forceinline__ float flog1p(float x) {
    return __builtin_amdgcn_logf(1.f + x) * LN2_F;   // v_log_f32 is log2
}
// atan2(y,x)/pi, poly max err ~2e-6 (in pi units)
__device__ __forceinline__ float fatan2pi(float y, float x) {
    const float ay = fabsf(y), ax = fabsf(x);
    const float mn = fminf(ay, ax), mx = fmaxf(ay, ax);
    float t = mn * __builtin_amdgcn_rcpf(mx);
    t = (mx == 0.f) ? 0.f : t;
    const float s = t * t;
    float p = -0.00373098f;
    p = fmaf(p, s,  0.01676008f);
    p = fmaf(p, s, -0.03706162f);
    p = fmaf(p, s,  0.06160679f);
    p = fmaf(p, s, -0.10587735f);
    p = fmaf(p, s,  0.31830265f);
    p *= t;
    p = (ay > ax) ? 0.5f - p : p;
    p = (x < 0.f) ? 1.0f - p : p;
    return copysignf(p, y);
}

// ---------------------------------------------------------------------------
// prep: weight conversions (Wp -> hi only; W1/W2 -> hi/lo) + softmax.
// blocks [0,128): Wp. [128,160): W1. [160,176): W2. 176: softmax.
// ---------------------------------------------------------------------------
__global__ __launch_bounds__(256) void prep_kernel(
        const float* __restrict__ Wp, const float* __restrict__ W1,
        const float* __restrict__ W2, const float* __restrict__ agg,
        u16* __restrict__ WpH,
        u16* __restrict__ W1H, u16* __restrict__ W1L,
        u16* __restrict__ W2H, u16* __restrict__ W2L,
        float* __restrict__ wts) {
    const int blk = blockIdx.x;
    const int tid = threadIdx.x;
    if (blk < 128) {
        const int total = MLP_ * FD_;
        for (int i = blk * 256 + tid; i < total; i += 128 * 256)
            WpH[i] = f2bf(Wp[i]);
    } else if (blk < 160) {
        const int total = HID_ * MLP_;
        for (int i = (blk - 128) * 256 + tid; i < total; i += 32 * 256) {
            const float v = W1[i];
            const u16 h = f2bf(v);
            W1H[i] = h; W1L[i] = f2bf(v - bf2f(h));
        }
    } else if (blk < 176) {
        const int total = HH_ * HID_;
        for (int i = (blk - 160) * 256 + tid; i < total; i += 16 * 256) {
            const float v = W2[i];
            const u16 h = f2bf(v);
            W2H[i] = h; W2L[i] = f2bf(v - bf2f(h));
        }
    } else {
        __shared__ float red[256];
        float mx = -INFINITY;
        for (int i = tid; i < NW_; i += 256) mx = fmaxf(mx, agg[i]);
        red[tid] = mx; __syncthreads();
        for (int s = 128; s > 0; s >>= 1) {
            if (tid < s) red[tid] = fmaxf(red[tid], red[tid + s]);
            __syncthreads();
        }
        mx = red[0]; __syncthreads();
        float sm = 0.f;
        for (int i = tid; i < NW_; i += 256) sm += expf(agg[i] - mx);
        red[tid] = sm; __syncthreads();
        for (int s = 128; s > 0; s >>= 1) {
            if (tid < s) red[tid] += red[tid + s];
            __syncthreads();
        }
        const float inv = 1.f / red[0];
        for (int i = tid; i < NW_; i += 256) wts[i] = expf(agg[i] - mx) * inv;
    }
}

// ---------------------------------------------------------------------------
// feat v3: SLIDING DFT (round-11 version, validated).
// ---------------------------------------------------------------------------
__global__ __launch_bounds__(256) void feat_kernel(const float* __restrict__ x,
                                                   u32* __restrict__ featP) {
    const int n0 = blockIdx.x * TN_;
    const int cg = blockIdx.y;
    const int bb = blockIdx.z;
    const int tid = threadIdx.x;
    const int tf = tid & 31;     // bin 0..31
    const int c8 = tid >> 5;     // channel-in-group 0..7
    const int c  = cg * 8 + c8;

    __shared__ float2 stab[64];
    __shared__ float xs[8][96];
    __shared__ float basisT[64][68];

    if (tid < 64) {
        float s, cc;
        sincosf(-PI_F * (float)tid / 32.0f, &s, &cc);
        stab[tid] = make_float2(cc, s);
    }
    __syncthreads();
    for (int e = tid; e < 2048; e += 256) {
        const int f = e >> 6, k = e & 63;
        const float2 w = stab[(f * k) & 63];
        basisT[k][2 * f]     = w.x;
        basisT[k][2 * f + 1] = w.y;
    }
    if (tid < 192) {
        const int cs = tid / 24, q = tid % 24;
        const int t0 = n0 + q * 4;
        const float* xb = x + ((size_t)bb * C_ + cg * 8 + cs) * T_;
        float4 v;
        if (t0 + 3 < T_) {
            v = *(const float4*)(xb + t0);
        } else {
            v.x = (t0 + 0 < T_) ? xb[t0 + 0] : 0.f;
            v.y = (t0 + 1 < T_) ? xb[t0 + 1] : 0.f;
            v.z = (t0 + 2 < T_) ? xb[t0 + 2] : 0.f;
            v.w = 0.f;
        }
        *(float4*)&xs[cs][q * 4] = v;
    }
    __syncthreads();

    const size_t rowb = (size_t)bb * NW_;

    // phase 1: bins 0..31, sliding across 32 windows
    {
        float re = 0.f, im = 0.f;
#pragma unroll
        for (int k = 0; k < 64; ++k) {
            const float xv = xs[c8][k];
            const float2 w = *(const float2*)&basisT[k][2 * tf];
            re = fmaf(xv, w.x, re);
            im = fmaf(xv, w.y, im);
        }
        const float2 st = stab[tf];
        const float cx = st.x, sx = -st.y;

        for (int j = 0; j < TN_; ++j) {
            const int gn = n0 + j;
            if (gn >= NW_) break;
            const float r   = __builtin_amdgcn_sqrtf(re * re + im * im);
            const float mag = flog1p(r);
            const float ph  = fatan2pi(im, re);
            featP[(rowb + gn) * (FD_ / 2) + 33 * c + tf] =
                (u32)f2bf(mag) | ((u32)f2bf(ph) << 16);
            const float tre = re - xs[c8][j] + xs[c8][j + 64];
            re = tre * cx - im * sx;
            im = tre * sx + im * cx;
        }
    }

    // phase 2: Nyquist bin
    {
        const int j   = tid & 31;
        const int c8n = tid >> 5;
        const int gn  = n0 + j;
        if (gn < NW_) {
            float s = 0.f;
#pragma unroll
            for (int k = 0; k < 32; ++k)
                s += xs[c8n][j + 2 * k] - xs[c8n][j + 2 * k + 1];
            const float a = flog1p(fabsf(s));
            const float p = (__float_as_uint(s) >> 31) ? 1.0f : 0.0f;
            featP[(rowb + gn) * (FD_ / 2) + 33 * (cg * 8 + c8n) + 32] =
                (u32)f2bf(a) | ((u32)f2bf(p) << 16);
        }
    }
}

// ---------------------------------------------------------------------------
// gemm1t: proj layer, 1-term x 1-term. BM=64 x BN=256, BK=32, 256 thr /
// 4 waves (1x4 of 64x64). 3-buffer depth-2 counted-vmcnt pipeline,
// STEPB=20KB, LDS=60KB -> 2 blocks/CU (grid 482 on 256 CUs): independent
// blocks overlap each other's barrier stalls. 16 MFMA/step.
// proj = tanh(feat @ WpH^T + bp) * pi -> bf16 plane.
// ---------------------------------------------------------------------------
__global__ __launch_bounds__(256, 2) void gemm1t_kernel(
        const u16* __restrict__ A, const u16* __restrict__ BH,
        const float* __restrict__ bias,
        u16* __restrict__ outH, int Mvalid, int Kd) {
    constexpr int STEPB = 4096 + 16384;     // A 4K | B 16K
    __shared__ char lds[3 * STEPB];         // 61440

    const int bm = blockIdx.x;
    const int tid = threadIdx.x;
    const int lane = tid & 63, wc = tid >> 6;   // 4 column-waves
    const int m0 = bm * 64;

    f32x4 acc[4][4];
#pragma unroll
    for (int i = 0; i < 4; ++i)
#pragma unroll
        for (int j = 0; j < 4; ++j) acc[i][j] = (f32x4){0.f, 0.f, 0.f, 0.f};

    const size_t rs = (size_t)Kd * 2;
    const char* gA = (const char*)A + (size_t)m0 * rs;
    const char* gB = (const char*)BH;

    auto st1 = [&](const char* g, char* l, int idx) {
        const int row = idx >> 2;
        const int kc  = (idx & 3) ^ ((row >> 1) & 3);
        gload16(g + (size_t)row * rs + (size_t)(kc << 4), l + idx * 16);
    };
    auto stage = [&](int buf, int t) {
        const size_t k0b = (size_t)t << 6;
        char* lb = lds + buf * STEPB;
        st1(gA + k0b, lb, tid);                 // A: 256 chunks (64 rows)
        st1(gB + k0b, lb + 4096, tid);          // B: 1024 chunks (256 rows)
        st1(gB + k0b, lb + 4096, tid + 256);
        st1(gB + k0b, lb + 4096, tid + 512);
        st1(gB + k0b, lb + 4096, tid + 768);
    };

    const int ra_ = lane & 15;                  // A rows 0..63
    const int rb_ = wc * 64 + (lane & 15);
    const int q   = lane >> 4;
    const int abase = ra_ * 64 + ((q ^ ((ra_ >> 1) & 3)) << 4);
    const int bbase = rb_ * 64 + ((q ^ ((rb_ >> 1) & 3)) << 4);

    const int nt = Kd >> 5;

    stage(0, 0);
    stage(1, 1);

    int cur = 0;
    for (int t = 0; t < nt; ++t) {
        if (t + 1 < nt)
            asm volatile("s_waitcnt vmcnt(5)" ::: "memory");
        else
            asm volatile("s_waitcnt vmcnt(0)" ::: "memory");
        __builtin_amdgcn_sched_barrier(0);
        __builtin_amdgcn_s_barrier();
        asm volatile("" ::: "memory");

        int pf = cur + 2; if (pf >= 3) pf -= 3;
        if (t + 2 < nt) stage(pf, t + 2);

        const char* lb = lds + cur * STEPB;
        bf16x8 a4[4], b4[4];
#pragma unroll
        for (int f = 0; f < 4; ++f) {
            a4[f] = *(const bf16x8*)(lb + abase + f * 1024);
            b4[f] = *(const bf16x8*)(lb + 4096 + bbase + f * 1024);
        }
        __builtin_amdgcn_s_setprio(1);
#pragma unroll
        for (int fm = 0; fm < 4; ++fm)
#pragma unroll
            for (int fn = 0; fn < 4; ++fn)
                acc[fm][fn] = __builtin_amdgcn_mfma_f32_16x16x32_bf16(a4[fm], b4[fn], acc[fm][fn], 0, 0, 0);
        __builtin_amdgcn_s_setprio(0);
        ++cur; if (cur >= 3) cur -= 3;
    }

    float bv[4];
#pragma unroll
    for (int fn = 0; fn < 4; ++fn) bv[fn] = bias[wc * 64 + fn * 16 + (lane & 15)];
#pragma unroll
    for (int fm = 0; fm < 4; ++fm) {
        const int rbase = m0 + fm * 16 + (lane >> 4) * 4;
#pragma unroll
        for (int fn = 0; fn < 4; ++fn) {
            const int col = wc * 64 + fn * 16 + (lane & 15);
#pragma unroll
            for (int r = 0; r < 4; ++r) {
                const int row = rbase + r;
                if (row < Mvalid) {
                    const float v = ftanh(acc[fm][fn][r] + bv[fn]) * PI_F;
                    outH[(size_t)row * 256 + col] = f2bf(v);
                }
            }
        }
    }
}

// ---------------------------------------------------------------------------
// gemm3p: 3-buffer depth-2 counted-vmcnt pipeline (round-11, validated).
// BM=128 x BN=256, BK=32, 512 thr / 8 waves, 2-term B. Used for h1.
// ---------------------------------------------------------------------------
__global__ __launch_bounds__(512, 2) void gemm3p_kernel(
        const u16* __restrict__ A,
        const u16* __restrict__ BH, const u16* __restrict__ BL,
        const float* __restrict__ bias, float scale,
        u16* __restrict__ outH, int Mvalid, int Kd) {
    constexpr int BNB   = 16384;
    constexpr int STEPB = 8192 + 2 * BNB;
    __shared__ char lds[3 * STEPB];

    const int bm = blockIdx.x;
    const int tid = threadIdx.x;
    const int lane = tid & 63, w = tid >> 6;
    const int wr = w >> 2, wc = w & 3;
    const int m0 = bm * 128;

    f32x4 acc[4][4];
#pragma unroll
    for (int i = 0; i < 4; ++i)
#pragma unroll
        for (int j = 0; j < 4; ++j) acc[i][j] = (f32x4){0.f, 0.f, 0.f, 0.f};

    const size_t rs = (size_t)Kd * 2;
    const char* gA  = (const char*)A + (size_t)m0 * rs;
    const char* gBH = (const char*)BH;
    const char* gBL = (const char*)BL;

    auto st1 = [&](const char* g, char* l, int idx) {
        const int row = idx >> 2;
        const int kc  = (idx & 3) ^ ((row >> 1) & 3);
        gload16(g + (size_t)row * rs + (size_t)(kc << 4), l + idx * 16);
    };
    auto stage = [&](int buf, int t) {
        const size_t k0b = (size_t)t << 6;
        char* lb = lds + buf * STEPB;
        st1(gA + k0b, lb, tid);
        st1(gBH + k0b, lb + 8192, tid);
        st1(gBH + k0b, lb + 8192, tid + 512);
        st1(gBL + k0b, lb + 8192 + BNB, tid);
        st1(gBL + k0b, lb + 8192 + BNB, tid + 512);
    };

    const int ra_ = wr * 64 + (lane & 15);
    const int rb_ = wc * 64 + (lane & 15);
    const int q   = lane >> 4;
    const int abase = ra_ * 64 + ((q ^ ((ra_ >> 1) & 3)) << 4);
    const int bbase = rb_ * 64 + ((q ^ ((rb_ >> 1) & 3)) << 4);

    const int nt = Kd >> 5;

    stage(0, 0);
    stage(1, 1);

    int cur = 0;
    for (int t = 0; t < nt; ++t) {
        if (t + 1 < nt)
            asm volatile("s_waitcnt vmcnt(5)" ::: "memory");
        else
            asm volatile("s_waitcnt vmcnt(0)" ::: "memory");
        __builtin_amdgcn_sched_barrier(0);
        __builtin_amdgcn_s_barrier();
        asm volatile("" ::: "memory");

        int pf = cur + 2; if (pf >= 3) pf -= 3;
        if (t + 2 < nt) stage(pf, t + 2);

        const char* lb = lds + cur * STEPB;
        bf16x8 a4[4], bh4[4], bl4[4];
#pragma unroll
        for (int f = 0; f < 4; ++f) {
            a4[f]  = *(const bf16x8*)(lb + abase + f * 1024);
            bh4[f] = *(const bf16x8*)(lb + 8192 + bbase + f * 1024);
            bl4[f] = *(const bf16x8*)(lb + 8192 + BNB + bbase + f * 1024);
        }
        __builtin_amdgcn_s_setprio(1);
#pragma unroll
        for (int fm = 0; fm < 4; ++fm)
#pragma unroll
            for (int fn = 0; fn < 4; ++fn) {
                acc[fm][fn] = __builtin_amdgcn_mfma_f32_16x16x32_bf16(a4[fm], bh4[fn], acc[fm][fn], 0, 0, 0);
                acc[fm][fn] = __builtin_amdgcn_mfma_f32_16x16x32_bf16(a4[fm], bl4[fn], acc[fm][fn], 0, 0, 0);
            }
        __builtin_amdgcn_s_setprio(0);
        ++cur; if (cur >= 3) cur -= 3;
    }

    float bv[4];
#pragma unroll
    for (int fn = 0; fn < 4; ++fn) bv[fn] = bias[wc * 64 + fn * 16 + (lane & 15)];
#pragma unroll
    for (int fm = 0; fm < 4; ++fm) {
        const int rbase = m0 + wr * 64 + fm * 16 + (lane >> 4) * 4;
#pragma unroll
        for (int fn = 0; fn < 4; ++fn) {
            const int col = wc * 64 + fn * 16 + (lane & 15);
#pragma unroll
            for (int r = 0; r < 4; ++r) {
                const int row = rbase + r;
                if (row < Mvalid) {
                    const float v = ftanh(acc[fm][fn][r] + bv[fn]) * scale;
                    outH[(size_t)row * 256 + col] = f2bf(v);
                }
            }
        }
    }
}

// ---------------------------------------------------------------------------
// gemm3f: fused final layer + weighted reduction (round-11, validated).
// ---------------------------------------------------------------------------
__global__ __launch_bounds__(256, 2) void gemm3f_kernel(
        const u16* __restrict__ A,
        const u16* __restrict__ BH, const u16* __restrict__ BL,
        const float* __restrict__ b2, const float* __restrict__ Wout,
        const float* __restrict__ bout, const float* __restrict__ wts,
        float* __restrict__ partial, int Mvalid, int Kd) {
    constexpr int BNB   = 8192;
    constexpr int STEPB = 8192 + 2 * BNB;   // 24576
    __shared__ char lds[3 * STEPB];         // 73728

    const int bm = blockIdx.x;
    const int tid = threadIdx.x;
    const int lane = tid & 63, w = tid >> 6;
    const int wr = w >> 1, wc = w & 1;
    const int m0 = bm * 128;

    f32x4 acc[4][4];
#pragma unroll
    for (int i = 0; i < 4; ++i)
#pragma unroll
        for (int j = 0; j < 4; ++j) acc[i][j] = (f32x4){0.f, 0.f, 0.f, 0.f};

    const size_t rs = (size_t)Kd * 2;
    const char* gA  = (const char*)A + (size_t)m0 * rs;
    const char* gBH = (const char*)BH;
    const char* gBL = (const char*)BL;

    auto st1 = [&](const char* g, char* l, int idx) {
        const int row = idx >> 2;
        const int kc  = (idx & 3) ^ ((row >> 1) & 3);
        gload16(g + (size_t)row * rs + (size_t)(kc << 4), l + idx * 16);
    };
    auto stage = [&](int buf, int t) {
        const size_t k0b = (size_t)t << 6;
        char* lb = lds + buf * STEPB;
        st1(gA + k0b, lb, tid);
        st1(gA + k0b, lb, tid + 256);
        st1(gBH + k0b, lb + 8192, tid);
        st1(gBH + k0b, lb + 8192, tid + 256);
        st1(gBL + k0b, lb + 8192 + BNB, tid);
        st1(gBL + k0b, lb + 8192 + BNB, tid + 256);
    };

    const int ra_ = wr * 64 + (lane & 15);
    const int rb_ = wc * 64 + (lane & 15);
    const int q   = lane >> 4;
    const int abase = ra_ * 64 + ((q ^ ((ra_ >> 1) & 3)) << 4);
    const int bbase = rb_ * 64 + ((q ^ ((rb_ >> 1) & 3)) << 4);

    const int nt = Kd >> 5;

    stage(0, 0);
    stage(1, 1);

    int cur = 0;
    for (int t = 0; t < nt; ++t) {
        if (t + 1 < nt)
            asm volatile("s_waitcnt vmcnt(6)" ::: "memory");
        else
            asm volatile("s_waitcnt vmcnt(0)" ::: "memory");
        __builtin_amdgcn_sched_barrier(0);
        __builtin_amdgcn_s_barrier();
        asm volatile("" ::: "memory");

        int pf = cur + 2; if (pf >= 3) pf -= 3;
        if (t + 2 < nt) stage(pf, t + 2);

        const char* lb = lds + cur * STEPB;
        bf16x8 a4[4], bh4[4], bl4[4];
#pragma unroll
        for (int f = 0; f < 4; ++f) {
            a4[f]  = *(const bf16x8*)(lb + abase + f * 1024);
            bh4[f] = *(const bf16x8*)(lb + 8192 + bbase + f * 1024);
            bl4[f] = *(const bf16x8*)(lb + 8192 + BNB + bbase + f * 1024);
        }
        __builtin_amdgcn_s_setprio(1);
#pragma unroll
        for (int fm = 0; fm < 4; ++fm)
#pragma unroll
            for (int fn = 0; fn < 4; ++fn) {
                acc[fm][fn] = __builtin_amdgcn_mfma_f32_16x16x32_bf16(a4[fm], bh4[fn], acc[fm][fn], 0, 0, 0);
                acc[fm][fn] = __builtin_amdgcn_mfma_f32_16x16x32_bf16(a4[fm], bl4[fn], acc[fm][fn], 0, 0, 0);
            }
        __builtin_amdgcn_s_setprio(0);
        ++cur; if (cur >= 3) cur -= 3;
    }

    // ---- fused epilogue ----
    __syncthreads();
    float* rsum = (float*)lds;               // [128][2]
    float* red  = (float*)(lds + 1024);      // [256]

    float bv[4], wv[4];
#pragma unroll
    for (int fn = 0; fn < 4; ++fn) {
        const int col = wc * 64 + fn * 16 + (lane & 15);
        bv[fn] = b2[col];
        wv[fn] = Wout[col];
    }
#pragma unroll
    for (int fm = 0; fm < 4; ++fm) {
#pragma unroll
        for (int r = 0; r < 4; ++r) {
            float c = 0.f;
#pragma unroll
            for (int fn = 0; fn < 4; ++fn)
                c += ftanh(acc[fm][fn][r] + bv[fn]) * wv[fn];
            c += __shfl_xor(c, 1);
            c += __shfl_xor(c, 2);
            c += __shfl_xor(c, 4);
            c += __shfl_xor(c, 8);
            if ((lane & 15) == 0)
                rsum[(wr * 64 + fm * 16 + (lane >> 4) * 4 + r) * 2 + wc] = c;
        }
    }
    __syncthreads();

    const float bO = bout[0];
    float val = 0.f;
    int rowb = -1;
    if (tid < 128) {
        const int gr = m0 + tid;
        if (gr < Mvalid) {
            const float dot = rsum[tid * 2] + rsum[tid * 2 + 1] + bO;
            rowb = gr / NW_;
            val = dot * wts[gr - rowb * NW_];
        }
    }
    __syncthreads();

    const int bFirst = m0 / NW_;
    red[tid] = (tid < 128 && rowb == bFirst) ? val : 0.f;
    __syncthreads();
    for (int s = 128; s > 0; s >>= 1) {
        if (tid < s) red[tid] += red[tid + s];
        __syncthreads();
    }
    if (tid == 0) partial[bm * 2] = red[0];
    __syncthreads();
    red[tid] = (tid < 128 && rowb == bFirst + 1) ? val : 0.f;
    __syncthreads();
    for (int s = 128; s > 0; s >>= 1) {
        if (tid < s) red[tid] += red[tid + s];
        __syncthreads();
    }
    if (tid == 0) partial[bm * 2 + 1] = red[0];
}

// ---------------------------------------------------------------------------
// finred: out[b0+b] = fixed-order sum of partial slots spanning batch b.
// ---------------------------------------------------------------------------
__global__ __launch_bounds__(64) void finred_kernel(const float* __restrict__ partial,
                                                    float* __restrict__ out,
                                                    int nbat, int nblocks) {
    const int b = threadIdx.x;
    if (b >= nbat) return;
    int lo = (b * NW_) / 128;
    int hi = ((b + 1) * NW_ - 1) / 128;
    if (hi > nblocks - 1) hi = nblocks - 1;
    float s = 0.f;
    for (int bm = lo; bm <= hi; ++bm) {
        const int slot = ((bm * 128) / NW_ == b) ? 0 : 1;
        s += partial[bm * 2 + slot];
    }
    out[b] = s;
}

// ---------------------------------------------------------------------------
extern "C" void kernel_launch(void* const* d_in, const int* in_sizes, int n_in,
                              void* d_out, int out_size, void* d_ws, size_t ws_size,
                              hipStream_t stream) {
    const float* x    = (const float*)d_in[0];
    const float* Wp   = (const float*)d_in[1];
    const float* bp   = (const float*)d_in[2];
    const float* W1   = (const float*)d_in[3];
    const float* b1   = (const float*)d_in[4];
    const float* W2   = (const float*)d_in[5];
    const float* b2   = (const float*)d_in[6];
    const float* Wout = (const float*)d_in[7];
    const float* bout = (const float*)d_in[8];
    const float* agg  = (const float*)d_in[9];
    float* out = (float*)d_out;

    char* wsb = (char*)d_ws;
    size_t off = 0;
    auto ra = [](size_t b) { return (b + 255) & ~(size_t)255; };
    auto alloc = [&](size_t bytes) -> char* {
        char* p = wsb + off;
        off += ra(bytes);
        return p;
    };

    u16* WpH = (u16*)alloc((size_t)MLP_ * FD_ * 2);
    u16* W1H = (u16*)alloc((size_t)HID_ * MLP_ * 2);
    u16* W1L = (u16*)alloc((size_t)HID_ * MLP_ * 2);
    u16* W2H = (u16*)alloc((size_t)HH_ * HID_ * 2);
    u16* W2L = (u16*)alloc((size_t)HH_ * HID_ * 2);
    float* wts = (float*)alloc((size_t)NW_ * 4);

    const size_t fixed = off;
    int NB = 32;
    for (;;) {
        const size_t M = (size_t)NB * NW_;
        const size_t Mp = ((M + 127) / 128) * 128;
        const size_t need = ra(Mp * FD_ * 2) +        // featH
                            ra(Mp * 256 * 2) +        // projH
                            ra(Mp * 256 * 2) +        // h1H
                            ra((Mp / 128) * 2 * 4);   // partial
        if (fixed + need <= ws_size || NB == 1) break;
        NB >>= 1;
    }
    const size_t Mmax  = (size_t)NB * NW_;
    const size_t MpMax = ((Mmax + 127) / 128) * 128;
    u16* featH = (u16*)alloc(MpMax * FD_ * 2);
    u16* projH = (u16*)alloc(MpMax * 256 * 2);
    u16* h1H   = (u16*)alloc(MpMax * 256 * 2);
    float* partial = (float*)alloc((MpMax / 128) * 2 * 4);

    prep_kernel<<<dim3(177), dim3(256), 0, stream>>>(
        Wp, W1, W2, agg, WpH, W1H, W1L, W2H, W2L, wts);

    for (int b0 = 0; b0 < B_; b0 += NB) {
        const int nb = (B_ - b0 < NB) ? (B_ - b0) : NB;
        const int M = nb * NW_;
        const int Mp = ((M + 127) / 128) * 128;

        feat_kernel<<<dim3(NT_, 4, nb), dim3(256), 0, stream>>>(
            x + (size_t)b0 * C_ * T_, (u32*)featH);

        // proj = tanh(feat @ WpH^T + bp) * pi   (K=2112, 1-term, BM=64)
        gemm1t_kernel<<<dim3(Mp / 64), dim3(256), 0, stream>>>(
            featH, WpH, bp, projH, M, FD_);

        // h1 = tanh(proj @ W1^T + b1)           (K=256, 2-term B)
        gemm3p_kernel<<<dim3(Mp / 128), dim3(512), 0, stream>>>(
            projH, W1H, W1L, b1, 1.0f, h1H, M, MLP_);

        // fused: h2 GEMM + weighted reduce -> partials
        gemm3f_kernel<<<dim3(Mp / 128), dim3(256), 0, stream>>>(
            h1H, W2H, W2L, b2, Wout, bout, wts, partial, M, HID_);

        finred_kernel<<<dim3(1), dim3(64), 0, stream>>>(
            partial, out + b0, nb, Mp / 128);
    }
}

// Round 14
// 138.292 us; speedup vs baseline: 1.2200x; 1.1221x over previous
//
#include <hip/hip_runtime.h>
#include <math.h>

#define B_   32
#define C_   32
#define T_   1024
#define NF_  33
#define F2_  66      // NF*2
#define FD_  2112    // C_*F2_
#define NW_  961
#define MLP_ 256
#define HID_ 256
#define HH_  128
#define TN_  32
#define NT_  31      // ceil(961/32)

#define PI_F     3.14159265358979323846f
#define LN2_F    0.69314718055994530942f
#define L2E2_F   2.88539008177792681472f   // 2*log2(e)

typedef unsigned short u16;
typedef unsigned int   u32;
typedef __attribute__((ext_vector_type(8))) short bf16x8;
typedef __attribute__((ext_vector_type(4))) float f32x4;

__device__ __forceinline__ u16 f2bf(float f) {
    u32 u = __float_as_uint(f);
    u = u + 0x7FFFu + ((u >> 16) & 1u);   // RNE
    return (u16)(u >> 16);
}
__device__ __forceinline__ float bf2f(u16 h) {
    return __uint_as_float((u32)h << 16);
}
__device__ __forceinline__ void gload16(const void* g, void* l) {
    __builtin_amdgcn_global_load_lds(
        (const __attribute__((address_space(1))) void*)g,
        (__attribute__((address_space(3))) void*)l, 16, 0, 0);
}
__device__ __forceinline__ float ftanh(float x) {
    float z = __builtin_amdgcn_exp2f(x * L2E2_F);
    return 1.f - 2.f * __builtin_amdgcn_rcpf(z + 1.f);
}
__device__ __forceinline__ float flog1p(float x) {
    return __builtin_amdgcn_logf(1.f + x) * LN2_F;   // v_log_f32 is log2
}
// atan2(y,x)/pi, poly max err ~2e-6 (in pi units)
__device__ __forceinline__ float fatan2pi(float y, float x) {
    const float ay = fabsf(y), ax = fabsf(x);
    const float mn = fminf(ay, ax), mx = fmaxf(ay, ax);
    float t = mn * __builtin_amdgcn_rcpf(mx);
    t = (mx == 0.f) ? 0.f : t;
    const float s = t * t;
    float p = -0.00373098f;
    p = fmaf(p, s,  0.01676008f);
    p = fmaf(p, s, -0.03706162f);
    p = fmaf(p, s,  0.06160679f);
    p = fmaf(p, s, -0.10587735f);
    p = fmaf(p, s,  0.31830265f);
    p *= t;
    p = (ay > ax) ? 0.5f - p : p;
    p = (x < 0.f) ? 1.0f - p : p;
    return copysignf(p, y);
}

// ---------------------------------------------------------------------------
// prep: weight conversions (ALL hi-plane only) + softmax.
// blocks [0,128): Wp. [128,160): W1. [160,176): W2. 176: softmax.
// ---------------------------------------------------------------------------
__global__ __launch_bounds__(256) void prep_kernel(
        const float* __restrict__ Wp, const float* __restrict__ W1,
        const float* __restrict__ W2, const float* __restrict__ agg,
        u16* __restrict__ WpH, u16* __restrict__ W1H, u16* __restrict__ W2H,
        float* __restrict__ wts) {
    const int blk = blockIdx.x;
    const int tid = threadIdx.x;
    if (blk < 128) {
        const int total = MLP_ * FD_;
        for (int i = blk * 256 + tid; i < total; i += 128 * 256)
            WpH[i] = f2bf(Wp[i]);
    } else if (blk < 160) {
        const int total = HID_ * MLP_;
        for (int i = (blk - 128) * 256 + tid; i < total; i += 32 * 256)
            W1H[i] = f2bf(W1[i]);
    } else if (blk < 176) {
        const int total = HH_ * HID_;
        for (int i = (blk - 160) * 256 + tid; i < total; i += 16 * 256)
            W2H[i] = f2bf(W2[i]);
    } else {
        __shared__ float red[256];
        float mx = -INFINITY;
        for (int i = tid; i < NW_; i += 256) mx = fmaxf(mx, agg[i]);
        red[tid] = mx; __syncthreads();
        for (int s = 128; s > 0; s >>= 1) {
            if (tid < s) red[tid] = fmaxf(red[tid], red[tid + s]);
            __syncthreads();
        }
        mx = red[0]; __syncthreads();
        float sm = 0.f;
        for (int i = tid; i < NW_; i += 256) sm += expf(agg[i] - mx);
        red[tid] = sm; __syncthreads();
        for (int s = 128; s > 0; s >>= 1) {
            if (tid < s) red[tid] += red[tid + s];
            __syncthreads();
        }
        const float inv = 1.f / red[0];
        for (int i = tid; i < NW_; i += 256) wts[i] = expf(agg[i] - mx) * inv;
    }
}

// ---------------------------------------------------------------------------
// feat v3: SLIDING DFT (validated, unchanged).
// ---------------------------------------------------------------------------
__global__ __launch_bounds__(256) void feat_kernel(const float* __restrict__ x,
                                                   u32* __restrict__ featP) {
    const int n0 = blockIdx.x * TN_;
    const int cg = blockIdx.y;
    const int bb = blockIdx.z;
    const int tid = threadIdx.x;
    const int tf = tid & 31;     // bin 0..31
    const int c8 = tid >> 5;     // channel-in-group 0..7
    const int c  = cg * 8 + c8;

    __shared__ float2 stab[64];
    __shared__ float xs[8][96];
    __shared__ float basisT[64][68];

    if (tid < 64) {
        float s, cc;
        sincosf(-PI_F * (float)tid / 32.0f, &s, &cc);
        stab[tid] = make_float2(cc, s);
    }
    __syncthreads();
    for (int e = tid; e < 2048; e += 256) {
        const int f = e >> 6, k = e & 63;
        const float2 w = stab[(f * k) & 63];
        basisT[k][2 * f]     = w.x;
        basisT[k][2 * f + 1] = w.y;
    }
    if (tid < 192) {
        const int cs = tid / 24, q = tid % 24;
        const int t0 = n0 + q * 4;
        const float* xb = x + ((size_t)bb * C_ + cg * 8 + cs) * T_;
        float4 v;
        if (t0 + 3 < T_) {
            v = *(const float4*)(xb + t0);
        } else {
            v.x = (t0 + 0 < T_) ? xb[t0 + 0] : 0.f;
            v.y = (t0 + 1 < T_) ? xb[t0 + 1] : 0.f;
            v.z = (t0 + 2 < T_) ? xb[t0 + 2] : 0.f;
            v.w = 0.f;
        }
        *(float4*)&xs[cs][q * 4] = v;
    }
    __syncthreads();

    const size_t rowb = (size_t)bb * NW_;

    // phase 1: bins 0..31, sliding across 32 windows
    {
        float re = 0.f, im = 0.f;
#pragma unroll
        for (int k = 0; k < 64; ++k) {
            const float xv = xs[c8][k];
            const float2 w = *(const float2*)&basisT[k][2 * tf];
            re = fmaf(xv, w.x, re);
            im = fmaf(xv, w.y, im);
        }
        const float2 st = stab[tf];
        const float cx = st.x, sx = -st.y;

        for (int j = 0; j < TN_; ++j) {
            const int gn = n0 + j;
            if (gn >= NW_) break;
            const float r   = __builtin_amdgcn_sqrtf(re * re + im * im);
            const float mag = flog1p(r);
            const float ph  = fatan2pi(im, re);
            featP[(rowb + gn) * (FD_ / 2) + 33 * c + tf] =
                (u32)f2bf(mag) | ((u32)f2bf(ph) << 16);
            const float tre = re - xs[c8][j] + xs[c8][j + 64];
            re = tre * cx - im * sx;
            im = tre * sx + im * cx;
        }
    }

    // phase 2: Nyquist bin
    {
        const int j   = tid & 31;
        const int c8n = tid >> 5;
        const int gn  = n0 + j;
        if (gn < NW_) {
            float s = 0.f;
#pragma unroll
            for (int k = 0; k < 32; ++k)
                s += xs[c8n][j + 2 * k] - xs[c8n][j + 2 * k + 1];
            const float a = flog1p(fabsf(s));
            const float p = (__float_as_uint(s) >> 31) ? 1.0f : 0.0f;
            featP[(rowb + gn) * (FD_ / 2) + 33 * (cg * 8 + c8n) + 32] =
                (u32)f2bf(a) | ((u32)f2bf(p) << 16);
        }
    }
}

// ---------------------------------------------------------------------------
// gemm1t: 1-term MFMA GEMM, BM=128 x BN=256, BK=32, 512 thr / 8 waves
// (2x4 of 64x64). 3-buffer depth-2 counted-vmcnt pipeline, STEPB=24KB,
// LDS=72KB -> 2 blocks/CU. 3 gload16/thread/stage -> vmcnt(3).
// C = tanh(A @ B^T + bias) * scale -> bf16 plane. Used for proj and h1.
// ---------------------------------------------------------------------------
__global__ __launch_bounds__(512, 2) void gemm1t_kernel(
        const u16* __restrict__ A, const u16* __restrict__ BH,
        const float* __restrict__ bias, float scale,
        u16* __restrict__ outH, int Mvalid, int Kd) {
    constexpr int STEPB = 8192 + 16384;     // A 8K | B 16K
    __shared__ char lds[3 * STEPB];         // 73728

    const int bm = blockIdx.x;
    const int tid = threadIdx.x;
    const int lane = tid & 63, w = tid >> 6;
    const int wr = w >> 2, wc = w & 3;      // 2 x 4 waves of 64x64
    const int m0 = bm * 128;

    f32x4 acc[4][4];
#pragma unroll
    for (int i = 0; i < 4; ++i)
#pragma unroll
        for (int j = 0; j < 4; ++j) acc[i][j] = (f32x4){0.f, 0.f, 0.f, 0.f};

    const size_t rs = (size_t)Kd * 2;
    const char* gA = (const char*)A + (size_t)m0 * rs;
    const char* gB = (const char*)BH;

    auto st1 = [&](const char* g, char* l, int idx) {
        const int row = idx >> 2;
        const int kc  = (idx & 3) ^ ((row >> 1) & 3);
        gload16(g + (size_t)row * rs + (size_t)(kc << 4), l + idx * 16);
    };
    auto stage = [&](int buf, int t) {
        const size_t k0b = (size_t)t << 6;
        char* lb = lds + buf * STEPB;
        st1(gA + k0b, lb, tid);                 // A: 512 chunks (128 rows)
        st1(gB + k0b, lb + 8192, tid);          // B: 1024 chunks (256 rows)
        st1(gB + k0b, lb + 8192, tid + 512);
    };

    const int ra_ = wr * 64 + (lane & 15);
    const int rb_ = wc * 64 + (lane & 15);
    const int q   = lane >> 4;
    const int abase = ra_ * 64 + ((q ^ ((ra_ >> 1) & 3)) << 4);
    const int bbase = rb_ * 64 + ((q ^ ((rb_ >> 1) & 3)) << 4);

    const int nt = Kd >> 5;

    stage(0, 0);
    stage(1, 1);

    int cur = 0;
    for (int t = 0; t < nt; ++t) {
        if (t + 1 < nt)
            asm volatile("s_waitcnt vmcnt(3)" ::: "memory");
        else
            asm volatile("s_waitcnt vmcnt(0)" ::: "memory");
        __builtin_amdgcn_sched_barrier(0);
        __builtin_amdgcn_s_barrier();
        asm volatile("" ::: "memory");

        int pf = cur + 2; if (pf >= 3) pf -= 3;
        if (t + 2 < nt) stage(pf, t + 2);

        const char* lb = lds + cur * STEPB;
        bf16x8 a4[4], b4[4];
#pragma unroll
        for (int f = 0; f < 4; ++f) {
            a4[f] = *(const bf16x8*)(lb + abase + f * 1024);
            b4[f] = *(const bf16x8*)(lb + 8192 + bbase + f * 1024);
        }
        __builtin_amdgcn_s_setprio(1);
#pragma unroll
        for (int fm = 0; fm < 4; ++fm)
#pragma unroll
            for (int fn = 0; fn < 4; ++fn)
                acc[fm][fn] = __builtin_amdgcn_mfma_f32_16x16x32_bf16(a4[fm], b4[fn], acc[fm][fn], 0, 0, 0);
        __builtin_amdgcn_s_setprio(0);
        ++cur; if (cur >= 3) cur -= 3;
    }

    float bv[4];
#pragma unroll
    for (int fn = 0; fn < 4; ++fn) bv[fn] = bias[wc * 64 + fn * 16 + (lane & 15)];
#pragma unroll
    for (int fm = 0; fm < 4; ++fm) {
        const int rbase = m0 + wr * 64 + fm * 16 + (lane >> 4) * 4;
#pragma unroll
        for (int fn = 0; fn < 4; ++fn) {
            const int col = wc * 64 + fn * 16 + (lane & 15);
#pragma unroll
            for (int r = 0; r < 4; ++r) {
                const int row = rbase + r;
                if (row < Mvalid) {
                    const float v = ftanh(acc[fm][fn][r] + bv[fn]) * scale;
                    outH[(size_t)row * 256 + col] = f2bf(v);
                }
            }
        }
    }
}

// ---------------------------------------------------------------------------
// gemm3f: fused final layer + weighted reduction, 1-term B. 3-buffer
// depth-2 main loop at BM=128 x BN=128 (2x2 waves, 256 thr), STEPB=16KB,
// LDS=48KB -> 3 blocks/CU. 4 loads/stage -> vmcnt(4).
// Epilogue: h2 = tanh(acc+b2), rowdot via shfl_xor + LDS combine,
// val = (rowdot+bout)*wts[n], deterministic per-b tree -> partial slots.
// ---------------------------------------------------------------------------
__global__ __launch_bounds__(256, 2) void gemm3f_kernel(
        const u16* __restrict__ A, const u16* __restrict__ BH,
        const float* __restrict__ b2, const float* __restrict__ Wout,
        const float* __restrict__ bout, const float* __restrict__ wts,
        float* __restrict__ partial, int Mvalid, int Kd) {
    constexpr int STEPB = 8192 + 8192;      // A 8K | B 8K
    __shared__ char lds[3 * STEPB];         // 49152

    const int bm = blockIdx.x;
    const int tid = threadIdx.x;
    const int lane = tid & 63, w = tid >> 6;
    const int wr = w >> 1, wc = w & 1;
    const int m0 = bm * 128;

    f32x4 acc[4][4];
#pragma unroll
    for (int i = 0; i < 4; ++i)
#pragma unroll
        for (int j = 0; j < 4; ++j) acc[i][j] = (f32x4){0.f, 0.f, 0.f, 0.f};

    const size_t rs = (size_t)Kd * 2;
    const char* gA = (const char*)A + (size_t)m0 * rs;
    const char* gB = (const char*)BH;

    auto st1 = [&](const char* g, char* l, int idx) {
        const int row = idx >> 2;
        const int kc  = (idx & 3) ^ ((row >> 1) & 3);
        gload16(g + (size_t)row * rs + (size_t)(kc << 4), l + idx * 16);
    };
    auto stage = [&](int buf, int t) {
        const size_t k0b = (size_t)t << 6;
        char* lb = lds + buf * STEPB;
        st1(gA + k0b, lb, tid);
        st1(gA + k0b, lb, tid + 256);
        st1(gB + k0b, lb + 8192, tid);
        st1(gB + k0b, lb + 8192, tid + 256);
    };

    const int ra_ = wr * 64 + (lane & 15);
    const int rb_ = wc * 64 + (lane & 15);
    const int q   = lane >> 4;
    const int abase = ra_ * 64 + ((q ^ ((ra_ >> 1) & 3)) << 4);
    const int bbase = rb_ * 64 + ((q ^ ((rb_ >> 1) & 3)) << 4);

    const int nt = Kd >> 5;

    stage(0, 0);
    stage(1, 1);

    int cur = 0;
    for (int t = 0; t < nt; ++t) {
        if (t + 1 < nt)
            asm volatile("s_waitcnt vmcnt(4)" ::: "memory");
        else
            asm volatile("s_waitcnt vmcnt(0)" ::: "memory");
        __builtin_amdgcn_sched_barrier(0);
        __builtin_amdgcn_s_barrier();
        asm volatile("" ::: "memory");

        int pf = cur + 2; if (pf >= 3) pf -= 3;
        if (t + 2 < nt) stage(pf, t + 2);

        const char* lb = lds + cur * STEPB;
        bf16x8 a4[4], b4[4];
#pragma unroll
        for (int f = 0; f < 4; ++f) {
            a4[f] = *(const bf16x8*)(lb + abase + f * 1024);
            b4[f] = *(const bf16x8*)(lb + 8192 + bbase + f * 1024);
        }
        __builtin_amdgcn_s_setprio(1);
#pragma unroll
        for (int fm = 0; fm < 4; ++fm)
#pragma unroll
            for (int fn = 0; fn < 4; ++fn)
                acc[fm][fn] = __builtin_amdgcn_mfma_f32_16x16x32_bf16(a4[fm], b4[fn], acc[fm][fn], 0, 0, 0);
        __builtin_amdgcn_s_setprio(0);
        ++cur; if (cur >= 3) cur -= 3;
    }

    // ---- fused epilogue ----
    __syncthreads();
    float* rsum = (float*)lds;               // [128][2]
    float* red  = (float*)(lds + 1024);      // [256]

    float bv[4], wv[4];
#pragma unroll
    for (int fn = 0; fn < 4; ++fn) {
        const int col = wc * 64 + fn * 16 + (lane & 15);
        bv[fn] = b2[col];
        wv[fn] = Wout[col];
    }
#pragma unroll
    for (int fm = 0; fm < 4; ++fm) {
#pragma unroll
        for (int r = 0; r < 4; ++r) {
            float c = 0.f;
#pragma unroll
            for (int fn = 0; fn < 4; ++fn)
                c += ftanh(acc[fm][fn][r] + bv[fn]) * wv[fn];
            c += __shfl_xor(c, 1);
            c += __shfl_xor(c, 2);
            c += __shfl_xor(c, 4);
            c += __shfl_xor(c, 8);
            if ((lane & 15) == 0)
                rsum[(wr * 64 + fm * 16 + (lane >> 4) * 4 + r) * 2 + wc] = c;
        }
    }
    __syncthreads();

    const float bO = bout[0];
    float val = 0.f;
    int rowb = -1;
    if (tid < 128) {
        const int gr = m0 + tid;
        if (gr < Mvalid) {
            const float dot = rsum[tid * 2] + rsum[tid * 2 + 1] + bO;
            rowb = gr / NW_;
            val = dot * wts[gr - rowb * NW_];
        }
    }
    __syncthreads();

    const int bFirst = m0 / NW_;
    red[tid] = (tid < 128 && rowb == bFirst) ? val : 0.f;
    __syncthreads();
    for (int s = 128; s > 0; s >>= 1) {
        if (tid < s) red[tid] += red[tid + s];
        __syncthreads();
    }
    if (tid == 0) partial[bm * 2] = red[0];
    __syncthreads();
    red[tid] = (tid < 128 && rowb == bFirst + 1) ? val : 0.f;
    __syncthreads();
    for (int s = 128; s > 0; s >>= 1) {
        if (tid < s) red[tid] += red[tid + s];
        __syncthreads();
    }
    if (tid == 0) partial[bm * 2 + 1] = red[0];
}

// ---------------------------------------------------------------------------
// finred: out[b0+b] = fixed-order sum of partial slots spanning batch b.
// ---------------------------------------------------------------------------
__global__ __launch_bounds__(64) void finred_kernel(const float* __restrict__ partial,
                                                    float* __restrict__ out,
                                                    int nbat, int nblocks) {
    const int b = threadIdx.x;
    if (b >= nbat) return;
    int lo = (b * NW_) / 128;
    int hi = ((b + 1) * NW_ - 1) / 128;
    if (hi > nblocks - 1) hi = nblocks - 1;
    float s = 0.f;
    for (int bm = lo; bm <= hi; ++bm) {
        const int slot = ((bm * 128) / NW_ == b) ? 0 : 1;
        s += partial[bm * 2 + slot];
    }
    out[b] = s;
}

// ---------------------------------------------------------------------------
extern "C" void kernel_launch(void* const* d_in, const int* in_sizes, int n_in,
                              void* d_out, int out_size, void* d_ws, size_t ws_size,
                              hipStream_t stream) {
    const float* x    = (const float*)d_in[0];
    const float* Wp   = (const float*)d_in[1];
    const float* bp   = (const float*)d_in[2];
    const float* W1   = (const float*)d_in[3];
    const float* b1   = (const float*)d_in[4];
    const float* W2   = (const float*)d_in[5];
    const float* b2   = (const float*)d_in[6];
    const float* Wout = (const float*)d_in[7];
    const float* bout = (const float*)d_in[8];
    const float* agg  = (const float*)d_in[9];
    float* out = (float*)d_out;

    char* wsb = (char*)d_ws;
    size_t off = 0;
    auto ra = [](size_t b) { return (b + 255) & ~(size_t)255; };
    auto alloc = [&](size_t bytes) -> char* {
        char* p = wsb + off;
        off += ra(bytes);
        return p;
    };

    u16* WpH = (u16*)alloc((size_t)MLP_ * FD_ * 2);
    u16* W1H = (u16*)alloc((size_t)HID_ * MLP_ * 2);
    u16* W2H = (u16*)alloc((size_t)HH_ * HID_ * 2);
    float* wts = (float*)alloc((size_t)NW_ * 4);

    const size_t fixed = off;
    int NB = 32;
    for (;;) {
        const size_t M = (size_t)NB * NW_;
        const size_t Mp = ((M + 127) / 128) * 128;
        const size_t need = ra(Mp * FD_ * 2) +        // featH
                            ra(Mp * 256 * 2) +        // projH
                            ra(Mp * 256 * 2) +        // h1H
                            ra((Mp / 128) * 2 * 4);   // partial
        if (fixed + need <= ws_size || NB == 1) break;
        NB >>= 1;
    }
    const size_t Mmax  = (size_t)NB * NW_;
    const size_t MpMax = ((Mmax + 127) / 128) * 128;
    u16* featH = (u16*)alloc(MpMax * FD_ * 2);
    u16* projH = (u16*)alloc(MpMax * 256 * 2);
    u16* h1H   = (u16*)alloc(MpMax * 256 * 2);
    float* partial = (float*)alloc((MpMax / 128) * 2 * 4);

    prep_kernel<<<dim3(177), dim3(256), 0, stream>>>(
        Wp, W1, W2, agg, WpH, W1H, W2H, wts);

    for (int b0 = 0; b0 < B_; b0 += NB) {
        const int nb = (B_ - b0 < NB) ? (B_ - b0) : NB;
        const int M = nb * NW_;
        const int Mp = ((M + 127) / 128) * 128;

        feat_kernel<<<dim3(NT_, 4, nb), dim3(256), 0, stream>>>(
            x + (size_t)b0 * C_ * T_, (u32*)featH);

        // proj = tanh(feat @ WpH^T + bp) * pi   (K=2112)
        gemm1t_kernel<<<dim3(Mp / 128), dim3(512), 0, stream>>>(
            featH, WpH, bp, PI_F, projH, M, FD_);

        // h1 = tanh(proj @ W1H^T + b1)          (K=256)
        gemm1t_kernel<<<dim3(Mp / 128), dim3(512), 0, stream>>>(
            projH, W1H, b1, 1.0f, h1H, M, MLP_);

        // fused: h2 GEMM + weighted reduce -> partials
        gemm3f_kernel<<<dim3(Mp / 128), dim3(256), 0, stream>>>(
            h1H, W2H, b2, Wout, bout, wts, partial, M, HID_);

        finred_kernel<<<dim3(1), dim3(64), 0, stream>>>(
            partial, out + b0, nb, Mp / 128);
    }
}